// Round 11
// baseline (490.156 us; speedup 1.0000x reference)
//
#include <hip/hip_runtime.h>
#include <cmath>

#define B_ 64
#define NP 512   // N == M == 512, D == 2

constexpr float L2E  = 1.4426950408889634f;   // log2(e)
constexpr float LN2f = 0.6931471805599453f;
constexpr float SKIP_T = 40.0f;               // log2-domain negligibility margin

struct EpsList { float e[64]; };

__device__ __forceinline__ float exp2_fast(float v) {
#if __has_builtin(__builtin_amdgcn_exp2f)
    return __builtin_amdgcn_exp2f(v);
#else
    return exp2f(v);
#endif
}
__device__ __forceinline__ float log2_fast(float v) {
#if __has_builtin(__builtin_amdgcn_logf)
    return __builtin_amdgcn_logf(v);
#else
    return log2f(v);
#endif
}
// written so clang fuses to v_max3_f32
__device__ __forceinline__ float max3f(float a, float b, float c) {
    return fmaxf(fmaxf(a, b), c);
}

// One-time spatial sort: per (batch, side), bitonic-sort the 512 points by
// x-coordinate in LDS; write the permutation. Sorting gives the sinkhorn
// kernel chunk-level spatial locality so far chunks can be skipped.
__global__ __launch_bounds__(256) void sort_k(
    const float* __restrict__ x, const float* __restrict__ y,
    unsigned short* __restrict__ permx, unsigned short* __restrict__ permy)
{
    __shared__ float key[NP];
    __shared__ int   val[NP];
    const int tid = threadIdx.x;
    const int b   = blockIdx.x & 63;
    const bool yside = blockIdx.x >= 64;
    const float* c = (yside ? y : x) + b * NP * 2;
    #pragma unroll
    for (int u = 0; u < 2; ++u) {
        int t = tid + u * 256;
        key[t] = c[2 * t];    // cx
        val[t] = t;
    }
    for (int k = 2; k <= NP; k <<= 1) {
        for (int j = k >> 1; j > 0; j >>= 1) {
            __syncthreads();
            #pragma unroll
            for (int u = 0; u < 2; ++u) {
                int i = tid + u * 256;
                int ixj = i ^ j;
                if (ixj > i) {
                    bool up = ((i & k) == 0);
                    float ki = key[i], kj = key[ixj];
                    if ((ki > kj) == up) {
                        key[i] = kj; key[ixj] = ki;
                        int vi = val[i]; val[i] = val[ixj]; val[ixj] = vi;
                    }
                }
            }
        }
    }
    __syncthreads();
    unsigned short* perm = (yside ? permy : permx) + b * NP;
    #pragma unroll
    for (int u = 0; u < 2; ++u) {
        int t = tid + u * 256;
        perm[t] = (unsigned short)val[t];
    }
}

// Persistent launch: 1024 blocks, 256 threads, 4 blocks/CU, whole grid
// resident (R8-R10 proven). b = bid&63 (batch-interleaved: 4 co-resident
// blocks come from 4 batches); q = bid>>6; q<8 f-side, q>=8 g-side; rq=q&7
// is a 64-row slice. sx=tid&7 owns j = sx (mod 8); tid>>3 owns 2 rows.
// ALL point data is accessed through the sorted permutation (gathered once
// at staging); potentials live in sorted index space (contiguous per pass).
//
// Sparsity skip (NEW): per (k-chunk, row-pair), if the whole wave-group's
// chunk-max is below running max - 40 (log2), skip the sub/exp2/add block —
// those terms flush to 0 in exp2 anyway. Sorting makes this fire on most
// chunks once eps is small (relevant j's are spatially local).
//
// Sync (R6-proven): RELAXED agent-scope atomics only (acq/rel emits
// buffer_wbl2/inv -> R5 coherence storm). Pass-parity buffers. Per-side
// counters: f-blocks wait only on the 8 g-blocks of their batch, vice versa.
__global__ __launch_bounds__(256, 4) void sinkhorn_pers(
    const float* __restrict__ a, const float* __restrict__ x,
    const float* __restrict__ bb, const float* __restrict__ y,
    float* __restrict__ fA, float* __restrict__ gA,
    float* __restrict__ fB, float* __restrict__ gB,
    const unsigned short* __restrict__ permx,
    const unsigned short* __restrict__ permy,
    unsigned int* __restrict__ bar, float* __restrict__ part2,
    EpsList el, int n_eps)
{
    __shared__ float4 sd[NP];     // {cx, cy, shp, 0} (rebuilt per pass)
    __shared__ float s_eps[64];
    __shared__ float swred[4];

    const int bid = blockIdx.x;
    const int b   = bid & 63;     // batch-interleaved mapping
    const int q   = bid >> 6;
    const bool gside = q >= 8;
    const int rq  = q & 7;
    const int tid = threadIdx.x;
    const int sx  = tid & 7;
    const int rowbase = rq * 64 + (tid >> 3) * 2;   // 2 rows per thread (sorted space)
    unsigned int* own_ctr  = bar + b * 64 + (gside ? 32 : 0);
    unsigned int* othr_ctr = bar + b * 64 + (gside ? 0 : 32);

    if (tid < 64) s_eps[tid] = el.e[tid];

    const unsigned short* osort = (gside ? permx : permy) + b * NP;
    const unsigned short* msort = (gside ? permy : permx) + b * NP;

    // ---- one-time staging (gather through permutation) ----
    const float2* oc2   = (const float2*)(gside ? (x + b * NP * 2) : (y + b * NP * 2));
    const float*  oprob = gside ? (a + b * NP) : (bb + b * NP);
    float ocx[2], ocy[2], on2[2], olw[2];
    #pragma unroll
    for (int u = 0; u < 2; ++u) {
        int jo = osort[tid + u * 256];
        float2 c = oc2[jo];
        ocx[u] = c.x; ocy[u] = c.y;
        on2[u] = fmaf(c.y, c.y, c.x * c.x);
        olw[u] = L2E * logf(oprob[jo]);
    }
    const float2* mc2  = (const float2*)(gside ? (y + b * NP * 2) : (x + b * NP * 2));
    const float* mprob = gside ? (bb + b * NP)    : (a + b * NP);
    const int r0 = msort[rowbase], r1 = msort[rowbase + 1];
    const float2 c0 = mc2[r0];
    const float2 c1 = mc2[r1];
    const float x0[2] = {c0.x, c1.x};
    const float x1[2] = {c0.y, c1.y};
    float half_n2[2];
    #pragma unroll
    for (int r = 0; r < 2; ++r) half_n2[r] = 0.5f * fmaf(x1[r], x1[r], x0[r] * x0[r]);

    float pv[2];
    const int n_pass = n_eps + 2;
    __syncthreads();

    for (int p = 0; p < n_pass; ++p) {
        const float eps = (p == 0) ? s_eps[0]
                        : (p <= n_eps ? s_eps[p - 1] : s_eps[n_eps - 1]);
        const float inv_eps = 1.0f / eps;
        const float ieL2E = inv_eps * L2E;
        const float nie   = -0.5f * ieL2E;

        // rebuild shp; other-side potential of pass p-1 in buffer ((p-1)&1),
        // already in sorted index space -> contiguous loads
        {
            float* opot = (gside ? ((p & 1) ? fA : fB)
                                 : ((p & 1) ? gA : gB)) + b * NP;
            #pragma unroll
            for (int u = 0; u < 2; ++u) {
                int t = tid + u * 256;
                float pot = (p != 0)
                    ? __hip_atomic_load(opot + t, __ATOMIC_RELAXED, __HIP_MEMORY_SCOPE_AGENT)
                    : 0.0f;
                float h2 = fmaf(pot, ieL2E, olw[u]);
                sd[t] = make_float4(ocx[u], ocy[u], fmaf(nie, on2[u], h2), 0.0f);
            }
        }
        __syncthreads();

        float x0p[2], x1p[2], m[2], s[2];
        #pragma unroll
        for (int r = 0; r < 2; ++r) {
            x0p[r] = x0[r] * ieL2E;
            x1p[r] = x1[r] * ieL2E;
            m[r] = -INFINITY;
            s[r] = 0.0f;
        }

        #pragma unroll 1
        for (int k = 0; k < 8; ++k) {
            float4 cj[8];
            #pragma unroll
            for (int u = 0; u < 8; ++u) cj[u] = sd[64 * k + 8 * u + sx];
            #pragma unroll
            for (int r = 0; r < 2; ++r) {
                float arg[8];
                #pragma unroll
                for (int u = 0; u < 8; ++u)
                    arg[u] = fmaf(x1p[r], cj[u].y, fmaf(x0p[r], cj[u].x, cj[u].z));
                float t0 = max3f(arg[0], arg[1], arg[2]);
                float t1 = max3f(arg[3], arg[4], arg[5]);
                float t2 = fmaxf(arg[6], arg[7]);
                float cmax = max3f(t0, t1, t2);
                // sparsity skip: chunk negligible for every row in the wave
                if (__all(cmax <= m[r] - SKIP_T)) continue;
                float mn = fmaxf(m[r], cmax);
                s[r] *= exp2_fast(m[r] - mn);   // first chunk: 0*exp2(-inf)=0
                #pragma unroll
                for (int u = 0; u < 8; ++u) s[r] += exp2_fast(arg[u] - mn);
                m[r] = mn;
            }
        }

        // two-phase combine across the 8 j-lanes:
        // max-butterfly -> single rescale -> sum-butterfly (1 exp2 per row)
        float val[2];
        #pragma unroll
        for (int r = 0; r < 2; ++r) {
            float mr = m[r];
            #pragma unroll
            for (int d = 1; d <= 4; d <<= 1) mr = fmaxf(mr, __shfl_xor(mr, d));
            float sr = s[r] * exp2_fast(m[r] - mr);
            #pragma unroll
            for (int d = 1; d <= 4; d <<= 1) sr += __shfl_xor(sr, d);
            val[r] = fmaf(-eps * LN2f, mr + log2_fast(sr), half_n2[r]);
        }

        if (p >= 1 && p <= n_eps) {
            #pragma unroll
            for (int r = 0; r < 2; ++r) val[r] = 0.5f * (pv[r] + val[r]);
        }
        #pragma unroll
        for (int r = 0; r < 2; ++r) pv[r] = val[r];

        if (p == n_pass - 1) break;   // final extrapolation: no write, no barrier

        if (sx == 0) {
            float* dst = (gside ? ((p & 1) ? gB : gA)
                                : ((p & 1) ? fB : fA)) + b * NP + rowbase;
            #pragma unroll
            for (int r = 0; r < 2; ++r)
                __hip_atomic_store(dst + r, val[r], __ATOMIC_RELAXED,
                                   __HIP_MEMORY_SCOPE_AGENT);
        }

        // ---- per-side handshake (wait only on the 8 other-side blocks) ----
        __syncthreads();   // vmcnt(0): our stores visible at the coherence point
        if (tid == 0) {
            __hip_atomic_fetch_add(own_ctr, 1u, __ATOMIC_RELAXED,
                                   __HIP_MEMORY_SCOPE_AGENT);
            const unsigned int target = 8u * (unsigned int)(p + 1);
            unsigned int guard = 0;
            while (__hip_atomic_load(othr_ctr, __ATOMIC_RELAXED,
                                     __HIP_MEMORY_SCOPE_AGENT) < target) {
                __builtin_amdgcn_s_sleep(1);
                if (++guard > (1u << 20)) break;   // valve (never hit when resident)
            }
        }
        __syncthreads();   // others wait for tid0's observation before reading
    }

    // ---- fused weighted dot product (gather probs through permutation) ----
    float local = 0.0f;
    if (sx == 0) {
        local = mprob[r0] * pv[0] + mprob[r1] * pv[1];
    }
    #pragma unroll
    for (int o = 32; o > 0; o >>= 1) local += __shfl_down(local, o);
    if ((tid & 63) == 0) swred[tid >> 6] = local;
    __syncthreads();
    if (tid == 0) part2[bid] = swred[0] + swred[1] + swred[2] + swred[3];
}

// Deterministic final reduction: out = sum_b w[b] * sum_q part2[q*64+b]
__global__ void finred_k(const float* __restrict__ part2,
                         const float* __restrict__ w, float* __restrict__ out) {
    int b = threadIdx.x;   // 64 threads, one wave
    float s = 0.0f;
    #pragma unroll
    for (int u = 0; u < 16; ++u) s += part2[u * 64 + b];
    s *= w[b];
    #pragma unroll
    for (int o = 32; o > 0; o >>= 1) s += __shfl_down(s, o);
    if (b == 0) out[0] = s;
}

extern "C" void kernel_launch(void* const* d_in, const int* in_sizes, int n_in,
                              void* d_out, int out_size, void* d_ws, size_t ws_size,
                              hipStream_t stream) {
    const float* a  = (const float*)d_in[0];  // prob1   [B,N]
    const float* x  = (const float*)d_in[1];  // coord1  [B,N,2]
    const float* bb = (const float*)d_in[2];  // prob2   [B,M]
    const float* y  = (const float*)d_in[3];  // coord2  [B,M,2]
    const float* w  = (const float*)d_in[4];  // weights [B]
    float* out = (float*)d_out;

    // workspace layout
    unsigned char* wsb = (unsigned char*)d_ws;
    unsigned int* bar = (unsigned int*)wsb;              // 64 x 2 counters, 128B apart
    float* part2 = (float*)(wsb + 64 * 64 * 4);          // 1024 floats
    float* fA = (float*)(wsb + 64 * 64 * 4 + 1024 * 4);
    const int NB = B_ * NP;
    float* gA = fA + NB;
    float* fB = gA + NB;
    float* gB = fB + NB;
    unsigned short* permx = (unsigned short*)(gB + NB);  // 64x512 u16
    unsigned short* permy = permx + NB;                  // 64x512 u16

    // eps schedule (geomloss epsilon_schedule semantics, computed in double)
    EpsList el{};
    int n_eps = 0;
    {
        const double start = 2.0 * std::log(4.0);
        const double stop  = 2.0 * std::log(0.01);
        const double step  = 2.0 * std::log(0.9);
        el.e[n_eps++] = 16.0f;                     // DIAMETER**P
        for (int k = 0;; ++k) {
            double v = start + (double)k * step;
            if (!(v > stop)) break;
            el.e[n_eps++] = (float)std::exp(v);
        }
        el.e[n_eps++] = (float)(0.01 * 0.01);      // BLUR**P
    }

    // counters must restart from 0 on every call (ws poisoned once at start)
    hipMemsetAsync(bar, 0, 64 * 64 * 4, stream);

    sort_k<<<dim3(128), dim3(256), 0, stream>>>(x, y, permx, permy);

    sinkhorn_pers<<<dim3(B_ * 16), dim3(256), 0, stream>>>(
        a, x, bb, y, fA, gA, fB, gB, permx, permy, bar, part2, el, n_eps);

    finred_k<<<1, 64, 0, stream>>>(part2, w, out);
}

// Round 12
// 473.202 us; speedup vs baseline: 1.0358x; 1.0358x over previous
//
#include <hip/hip_runtime.h>
#include <cmath>

#define B_ 64
#define NP 512   // N == M == 512, D == 2

constexpr float L2E  = 1.4426950408889634f;   // log2(e)
constexpr float LN2f = 0.6931471805599453f;
constexpr float SKIP_T = 40.0f;               // log2-domain negligibility margin

struct EpsList { float e[64]; };

__device__ __forceinline__ float exp2_fast(float v) {
#if __has_builtin(__builtin_amdgcn_exp2f)
    return __builtin_amdgcn_exp2f(v);
#else
    return exp2f(v);
#endif
}
__device__ __forceinline__ float log2_fast(float v) {
#if __has_builtin(__builtin_amdgcn_logf)
    return __builtin_amdgcn_logf(v);
#else
    return log2f(v);
#endif
}
// written so clang fuses to v_max3_f32
__device__ __forceinline__ float max3f(float a, float b, float c) {
    return fmaxf(fmaxf(a, b), c);
}

// One-time spatial sort: per (batch, side), bitonic-sort the 512 points by
// x-coordinate in LDS; write the permutation. Sorting gives the sinkhorn
// kernel chunk-level spatial locality so far chunks can be skipped.
__global__ __launch_bounds__(256) void sort_k(
    const float* __restrict__ x, const float* __restrict__ y,
    unsigned short* __restrict__ permx, unsigned short* __restrict__ permy)
{
    __shared__ float key[NP];
    __shared__ int   val[NP];
    const int tid = threadIdx.x;
    const int b   = blockIdx.x & 63;
    const bool yside = blockIdx.x >= 64;
    const float* c = (yside ? y : x) + b * NP * 2;
    #pragma unroll
    for (int u = 0; u < 2; ++u) {
        int t = tid + u * 256;
        key[t] = c[2 * t];    // cx
        val[t] = t;
    }
    for (int k = 2; k <= NP; k <<= 1) {
        for (int j = k >> 1; j > 0; j >>= 1) {
            __syncthreads();
            #pragma unroll
            for (int u = 0; u < 2; ++u) {
                int i = tid + u * 256;
                int ixj = i ^ j;
                if (ixj > i) {
                    bool up = ((i & k) == 0);
                    float ki = key[i], kj = key[ixj];
                    if ((ki > kj) == up) {
                        key[i] = kj; key[ixj] = ki;
                        int vi = val[i]; val[i] = val[ixj]; val[ixj] = vi;
                    }
                }
            }
        }
    }
    __syncthreads();
    unsigned short* perm = (yside ? permy : permx) + b * NP;
    #pragma unroll
    for (int u = 0; u < 2; ++u) {
        int t = tid + u * 256;
        perm[t] = (unsigned short)val[t];
    }
}

// Persistent launch: 1024 blocks, 256 threads, 4 blocks/CU, whole grid
// resident (R8-R10 proven). b = bid&63 (batch-interleaved: 4 co-resident
// blocks come from 4 batches); q = bid>>6; q<8 f-side, q>=8 g-side; rq=q&7
// is a 64-row slice. sx=tid&7 owns j = sx (mod 8); tid>>3 owns 2 rows.
// ALL point data is accessed through the sorted permutation (gathered once
// at staging); potentials live in sorted index space (contiguous per pass).
//
// Sparsity skip + ROTATED chunk order (the R11 fix): block rq starts its
// k-loop at chunk rq — its rows' (sorted) relevant chunk — so m[] hits the
// true max on the FIRST chunk and the remaining 7 chunks can all take the
// "negligible" early-out. Without rotation, leading chunks can never skip
// (cmax is increasing toward the relevant chunk) and the rq=7 block has no
// trailing chunks at all — it stalls the per-pass barrier for the whole
// batch, which is why R11 measured null.
//
// Sync (R6-proven): RELAXED agent-scope atomics only (acq/rel emits
// buffer_wbl2/inv -> R5 coherence storm). Pass-parity buffers. Per-side
// counters: f-blocks wait only on the 8 g-blocks of their batch, vice versa.
__global__ __launch_bounds__(256, 4) void sinkhorn_pers(
    const float* __restrict__ a, const float* __restrict__ x,
    const float* __restrict__ bb, const float* __restrict__ y,
    float* __restrict__ fA, float* __restrict__ gA,
    float* __restrict__ fB, float* __restrict__ gB,
    const unsigned short* __restrict__ permx,
    const unsigned short* __restrict__ permy,
    unsigned int* __restrict__ bar, float* __restrict__ part2,
    EpsList el, int n_eps)
{
    __shared__ float4 sd[NP];     // {cx, cy, shp, 0} (rebuilt per pass)
    __shared__ float s_eps[64];
    __shared__ float swred[4];

    const int bid = blockIdx.x;
    const int b   = bid & 63;     // batch-interleaved mapping
    const int q   = bid >> 6;
    const bool gside = q >= 8;
    const int rq  = q & 7;
    const int tid = threadIdx.x;
    const int sx  = tid & 7;
    const int rowbase = rq * 64 + (tid >> 3) * 2;   // 2 rows per thread (sorted space)
    unsigned int* own_ctr  = bar + b * 64 + (gside ? 32 : 0);
    unsigned int* othr_ctr = bar + b * 64 + (gside ? 0 : 32);

    if (tid < 64) s_eps[tid] = el.e[tid];

    const unsigned short* osort = (gside ? permx : permy) + b * NP;
    const unsigned short* msort = (gside ? permy : permx) + b * NP;

    // ---- one-time staging (gather through permutation) ----
    const float2* oc2   = (const float2*)(gside ? (x + b * NP * 2) : (y + b * NP * 2));
    const float*  oprob = gside ? (a + b * NP) : (bb + b * NP);
    float ocx[2], ocy[2], on2[2], olw[2];
    #pragma unroll
    for (int u = 0; u < 2; ++u) {
        int jo = osort[tid + u * 256];
        float2 c = oc2[jo];
        ocx[u] = c.x; ocy[u] = c.y;
        on2[u] = fmaf(c.y, c.y, c.x * c.x);
        olw[u] = L2E * logf(oprob[jo]);
    }
    const float2* mc2  = (const float2*)(gside ? (y + b * NP * 2) : (x + b * NP * 2));
    const float* mprob = gside ? (bb + b * NP)    : (a + b * NP);
    const int r0 = msort[rowbase], r1 = msort[rowbase + 1];
    const float2 c0 = mc2[r0];
    const float2 c1 = mc2[r1];
    const float x0[2] = {c0.x, c1.x};
    const float x1[2] = {c0.y, c1.y};
    float half_n2[2];
    #pragma unroll
    for (int r = 0; r < 2; ++r) half_n2[r] = 0.5f * fmaf(x1[r], x1[r], x0[r] * x0[r]);

    float pv[2];
    const int n_pass = n_eps + 2;
    __syncthreads();

    for (int p = 0; p < n_pass; ++p) {
        const float eps = (p == 0) ? s_eps[0]
                        : (p <= n_eps ? s_eps[p - 1] : s_eps[n_eps - 1]);
        const float inv_eps = 1.0f / eps;
        const float ieL2E = inv_eps * L2E;
        const float nie   = -0.5f * ieL2E;

        // rebuild shp; other-side potential of pass p-1 in buffer ((p-1)&1),
        // already in sorted index space -> contiguous loads
        {
            float* opot = (gside ? ((p & 1) ? fA : fB)
                                 : ((p & 1) ? gA : gB)) + b * NP;
            #pragma unroll
            for (int u = 0; u < 2; ++u) {
                int t = tid + u * 256;
                float pot = (p != 0)
                    ? __hip_atomic_load(opot + t, __ATOMIC_RELAXED, __HIP_MEMORY_SCOPE_AGENT)
                    : 0.0f;
                float h2 = fmaf(pot, ieL2E, olw[u]);
                sd[t] = make_float4(ocx[u], ocy[u], fmaf(nie, on2[u], h2), 0.0f);
            }
        }
        __syncthreads();

        float x0p[2], x1p[2], m[2], s[2];
        #pragma unroll
        for (int r = 0; r < 2; ++r) {
            x0p[r] = x0[r] * ieL2E;
            x1p[r] = x1[r] * ieL2E;
            m[r] = -INFINITY;
            s[r] = 0.0f;
        }

        #pragma unroll 1
        for (int kk = 0; kk < 8; ++kk) {
            const int k = (kk + rq) & 7;   // ROTATED: start at this block's own chunk
            float4 cj[8];
            #pragma unroll
            for (int u = 0; u < 8; ++u) cj[u] = sd[64 * k + 8 * u + sx];
            #pragma unroll
            for (int r = 0; r < 2; ++r) {
                float arg[8];
                #pragma unroll
                for (int u = 0; u < 8; ++u)
                    arg[u] = fmaf(x1p[r], cj[u].y, fmaf(x0p[r], cj[u].x, cj[u].z));
                float t0 = max3f(arg[0], arg[1], arg[2]);
                float t1 = max3f(arg[3], arg[4], arg[5]);
                float t2 = fmaxf(arg[6], arg[7]);
                float cmax = max3f(t0, t1, t2);
                // sparsity skip: chunk negligible for every row in the wave
                if (__all(cmax <= m[r] - SKIP_T)) continue;
                float mn = fmaxf(m[r], cmax);
                s[r] *= exp2_fast(m[r] - mn);   // first chunk: 0*exp2(-inf)=0
                #pragma unroll
                for (int u = 0; u < 8; ++u) s[r] += exp2_fast(arg[u] - mn);
                m[r] = mn;
            }
        }

        // two-phase combine across the 8 j-lanes:
        // max-butterfly -> single rescale -> sum-butterfly (1 exp2 per row)
        float val[2];
        #pragma unroll
        for (int r = 0; r < 2; ++r) {
            float mr = m[r];
            #pragma unroll
            for (int d = 1; d <= 4; d <<= 1) mr = fmaxf(mr, __shfl_xor(mr, d));
            float sr = s[r] * exp2_fast(m[r] - mr);
            #pragma unroll
            for (int d = 1; d <= 4; d <<= 1) sr += __shfl_xor(sr, d);
            val[r] = fmaf(-eps * LN2f, mr + log2_fast(sr), half_n2[r]);
        }

        if (p >= 1 && p <= n_eps) {
            #pragma unroll
            for (int r = 0; r < 2; ++r) val[r] = 0.5f * (pv[r] + val[r]);
        }
        #pragma unroll
        for (int r = 0; r < 2; ++r) pv[r] = val[r];

        if (p == n_pass - 1) break;   // final extrapolation: no write, no barrier

        if (sx == 0) {
            float* dst = (gside ? ((p & 1) ? gB : gA)
                                : ((p & 1) ? fB : fA)) + b * NP + rowbase;
            #pragma unroll
            for (int r = 0; r < 2; ++r)
                __hip_atomic_store(dst + r, val[r], __ATOMIC_RELAXED,
                                   __HIP_MEMORY_SCOPE_AGENT);
        }

        // ---- per-side handshake (wait only on the 8 other-side blocks) ----
        __syncthreads();   // vmcnt(0): our stores visible at the coherence point
        if (tid == 0) {
            __hip_atomic_fetch_add(own_ctr, 1u, __ATOMIC_RELAXED,
                                   __HIP_MEMORY_SCOPE_AGENT);
            const unsigned int target = 8u * (unsigned int)(p + 1);
            unsigned int guard = 0;
            while (__hip_atomic_load(othr_ctr, __ATOMIC_RELAXED,
                                     __HIP_MEMORY_SCOPE_AGENT) < target) {
                __builtin_amdgcn_s_sleep(1);
                if (++guard > (1u << 20)) break;   // valve (never hit when resident)
            }
        }
        __syncthreads();   // others wait for tid0's observation before reading
    }

    // ---- fused weighted dot product (gather probs through permutation) ----
    float local = 0.0f;
    if (sx == 0) {
        local = mprob[r0] * pv[0] + mprob[r1] * pv[1];
    }
    #pragma unroll
    for (int o = 32; o > 0; o >>= 1) local += __shfl_down(local, o);
    if ((tid & 63) == 0) swred[tid >> 6] = local;
    __syncthreads();
    if (tid == 0) part2[bid] = swred[0] + swred[1] + swred[2] + swred[3];
}

// Deterministic final reduction: out = sum_b w[b] * sum_q part2[q*64+b]
__global__ void finred_k(const float* __restrict__ part2,
                         const float* __restrict__ w, float* __restrict__ out) {
    int b = threadIdx.x;   // 64 threads, one wave
    float s = 0.0f;
    #pragma unroll
    for (int u = 0; u < 16; ++u) s += part2[u * 64 + b];
    s *= w[b];
    #pragma unroll
    for (int o = 32; o > 0; o >>= 1) s += __shfl_down(s, o);
    if (b == 0) out[0] = s;
}

extern "C" void kernel_launch(void* const* d_in, const int* in_sizes, int n_in,
                              void* d_out, int out_size, void* d_ws, size_t ws_size,
                              hipStream_t stream) {
    const float* a  = (const float*)d_in[0];  // prob1   [B,N]
    const float* x  = (const float*)d_in[1];  // coord1  [B,N,2]
    const float* bb = (const float*)d_in[2];  // prob2   [B,M]
    const float* y  = (const float*)d_in[3];  // coord2  [B,M,2]
    const float* w  = (const float*)d_in[4];  // weights [B]
    float* out = (float*)d_out;

    // workspace layout
    unsigned char* wsb = (unsigned char*)d_ws;
    unsigned int* bar = (unsigned int*)wsb;              // 64 x 2 counters, 128B apart
    float* part2 = (float*)(wsb + 64 * 64 * 4);          // 1024 floats
    float* fA = (float*)(wsb + 64 * 64 * 4 + 1024 * 4);
    const int NB = B_ * NP;
    float* gA = fA + NB;
    float* fB = gA + NB;
    float* gB = fB + NB;
    unsigned short* permx = (unsigned short*)(gB + NB);  // 64x512 u16
    unsigned short* permy = permx + NB;                  // 64x512 u16

    // eps schedule (geomloss epsilon_schedule semantics, computed in double)
    EpsList el{};
    int n_eps = 0;
    {
        const double start = 2.0 * std::log(4.0);
        const double stop  = 2.0 * std::log(0.01);
        const double step  = 2.0 * std::log(0.9);
        el.e[n_eps++] = 16.0f;                     // DIAMETER**P
        for (int k = 0;; ++k) {
            double v = start + (double)k * step;
            if (!(v > stop)) break;
            el.e[n_eps++] = (float)std::exp(v);
        }
        el.e[n_eps++] = (float)(0.01 * 0.01);      // BLUR**P
    }

    // counters must restart from 0 on every call (ws poisoned once at start)
    hipMemsetAsync(bar, 0, 64 * 64 * 4, stream);

    sort_k<<<dim3(128), dim3(256), 0, stream>>>(x, y, permx, permy);

    sinkhorn_pers<<<dim3(B_ * 16), dim3(256), 0, stream>>>(
        a, x, bb, y, fA, gA, fB, gB, permx, permy, bar, part2, el, n_eps);

    finred_k<<<1, 64, 0, stream>>>(part2, w, out);
}

// Round 13
// 438.845 us; speedup vs baseline: 1.1169x; 1.0783x over previous
//
#include <hip/hip_runtime.h>
#include <cmath>

#define B_ 64
#define NP 512   // N == M == 512, D == 2

constexpr float L2E  = 1.4426950408889634f;   // log2(e)
constexpr float LN2f = 0.6931471805599453f;

struct EpsList { float e[64]; };

__device__ __forceinline__ float exp2_fast(float v) {
#if __has_builtin(__builtin_amdgcn_exp2f)
    return __builtin_amdgcn_exp2f(v);
#else
    return exp2f(v);
#endif
}
__device__ __forceinline__ float log2_fast(float v) {
#if __has_builtin(__builtin_amdgcn_logf)
    return __builtin_amdgcn_logf(v);
#else
    return log2f(v);
#endif
}
// written so clang fuses to v_max3_f32
__device__ __forceinline__ float max3f(float a, float b, float c) {
    return fmaxf(fmaxf(a, b), c);
}

// Persistent launch: 1024 blocks, 256 threads, __launch_bounds__(256,4) ->
// 4 blocks/CU by resources; whole grid resident (R8-R12 proven).
//
// Block mapping (R9-proven): b = bid & 63, q = bid >> 6 — the 4 blocks
// sharing a CU come from 4 different batches, so cross-batch compute fills
// each batch's sync idle. q<8 -> f-side, q>=8 -> g-side; rq = q&7 is a
// 64-row slice. sx = tid&7 owns j = sx (mod 8), 64 j's per lane; tid>>3
// owns 2 consecutive rows; one float4 LDS broadcast read serves 2 rows
// (8-distinct-address broadcast, conflict-free).
//
// R11/R12 lesson encoded here: NO sort, NO permutation, NO sparsity skip.
// The converging potentials flatten the (g_j - C_ij)/eps landscape, so the
// log2-domain spread across chunks stays under ~40 for all passes — the
// chunk-level skip never fires on this problem and its machinery is pure
// overhead. This is the R10 structure + two free micro-trims: peeled first
// chunk (no exp2(-inf) rescale, no compare) and tree-shaped exp2 sums.
//
// Combine: two-phase (max-butterfly -> single rescale -> sum-butterfly),
// 1 exp2 per row. Max trees via v_max3_f32.
//
// Buffers: pure pass-parity (pass p writes buffer p&1, reads (p-1)&1).
// Cross-block sync (R6-proven): RELAXED agent-scope atomics ONLY — no
// fences, no acq/rel (those emit buffer_wbl2/buffer_inv -> R5 coherence
// storm). Release ordering via __syncthreads' s_waitcnt vmcnt(0); per-SIDE
// counters: f-blocks wait only on the 8 g-blocks of their batch, vice versa.
__global__ __launch_bounds__(256, 4) void sinkhorn_pers(
    const float* __restrict__ a, const float* __restrict__ x,
    const float* __restrict__ bb, const float* __restrict__ y,
    float* __restrict__ fA, float* __restrict__ gA,
    float* __restrict__ fB, float* __restrict__ gB,
    unsigned int* __restrict__ bar, float* __restrict__ part2,
    EpsList el, int n_eps)
{
    __shared__ float4 sd[NP];     // {cx, cy, shp, 0} (rebuilt per pass)
    __shared__ float s_eps[64];
    __shared__ float swred[4];

    const int bid = blockIdx.x;
    const int b   = bid & 63;     // batch-interleaved mapping
    const int q   = bid >> 6;
    const bool gside = q >= 8;
    const int rq  = q & 7;
    const int tid = threadIdx.x;
    const int sx  = tid & 7;
    const int rowbase = rq * 64 + (tid >> 3) * 2;   // 2 rows per thread
    // per-batch, per-side counters, each on its own 128B line
    unsigned int* own_ctr  = bar + b * 64 + (gside ? 32 : 0);
    unsigned int* othr_ctr = bar + b * 64 + (gside ? 0 : 32);

    if (tid < 64) s_eps[tid] = el.e[tid];

    // ---- one-time staging (registers) ----
    // reduced-over side: 2 points per thread
    const float2* oc2   = (const float2*)(gside ? (x + b * NP * 2) : (y + b * NP * 2));
    const float*  oprob = gside ? (a + b * NP) : (bb + b * NP);
    float ocx[2], ocy[2], on2[2], olw[2];
    #pragma unroll
    for (int u = 0; u < 2; ++u) {
        float2 c = oc2[tid + u * 256];
        ocx[u] = c.x; ocy[u] = c.y;
        on2[u] = fmaf(c.y, c.y, c.x * c.x);
        olw[u] = L2E * logf(oprob[tid + u * 256]);
    }
    // row side: 2 rows per thread
    const float* mcoord = gside ? (y + b * NP * 2) : (x + b * NP * 2);
    const float* mprob  = gside ? (bb + b * NP)    : (a + b * NP);
    const float4 rc01 = *(const float4*)(mcoord + rowbase * 2);   // rows 0,1
    const float x0[2] = {rc01.x, rc01.z};
    const float x1[2] = {rc01.y, rc01.w};
    float half_n2[2];
    #pragma unroll
    for (int r = 0; r < 2; ++r) half_n2[r] = 0.5f * fmaf(x1[r], x1[r], x0[r] * x0[r]);

    float pv[2];
    const int n_pass = n_eps + 2;
    __syncthreads();

    for (int p = 0; p < n_pass; ++p) {
        const float eps = (p == 0) ? s_eps[0]
                        : (p <= n_eps ? s_eps[p - 1] : s_eps[n_eps - 1]);
        const float inv_eps = 1.0f / eps;
        const float ieL2E = inv_eps * L2E;
        const float nie   = -0.5f * ieL2E;

        // rebuild shp; other-side potential of pass p-1 is in buffer ((p-1)&1)
        {
            float* opot = (gside ? ((p & 1) ? fA : fB)
                                 : ((p & 1) ? gA : gB)) + b * NP;
            #pragma unroll
            for (int u = 0; u < 2; ++u) {
                int t = tid + u * 256;
                float pot = (p != 0)
                    ? __hip_atomic_load(opot + t, __ATOMIC_RELAXED, __HIP_MEMORY_SCOPE_AGENT)
                    : 0.0f;
                float h2 = fmaf(pot, ieL2E, olw[u]);
                sd[t] = make_float4(ocx[u], ocy[u], fmaf(nie, on2[u], h2), 0.0f);
            }
        }
        __syncthreads();

        float x0p[2], x1p[2], m[2], s[2];
        #pragma unroll
        for (int r = 0; r < 2; ++r) {
            x0p[r] = x0[r] * ieL2E;
            x1p[r] = x1[r] * ieL2E;
        }

        // ---- peeled chunk 0: init m,s directly (no rescale, no compare) ----
        {
            float4 cj[8];
            #pragma unroll
            for (int u = 0; u < 8; ++u) cj[u] = sd[8 * u + sx];
            #pragma unroll
            for (int r = 0; r < 2; ++r) {
                float arg[8];
                #pragma unroll
                for (int u = 0; u < 8; ++u)
                    arg[u] = fmaf(x1p[r], cj[u].y, fmaf(x0p[r], cj[u].x, cj[u].z));
                float t0 = max3f(arg[0], arg[1], arg[2]);
                float t1 = max3f(arg[3], arg[4], arg[5]);
                float t2 = fmaxf(arg[6], arg[7]);
                float mn = max3f(t0, t1, t2);
                float e0 = exp2_fast(arg[0] - mn) + exp2_fast(arg[1] - mn);
                float e1 = exp2_fast(arg[2] - mn) + exp2_fast(arg[3] - mn);
                float e2 = exp2_fast(arg[4] - mn) + exp2_fast(arg[5] - mn);
                float e3 = exp2_fast(arg[6] - mn) + exp2_fast(arg[7] - mn);
                s[r] = (e0 + e1) + (e2 + e3);
                m[r] = mn;
            }
        }

        #pragma unroll 1
        for (int k = 1; k < 8; ++k) {
            float4 cj[8];
            #pragma unroll
            for (int u = 0; u < 8; ++u) cj[u] = sd[64 * k + 8 * u + sx];
            #pragma unroll
            for (int r = 0; r < 2; ++r) {
                float arg[8];
                #pragma unroll
                for (int u = 0; u < 8; ++u)
                    arg[u] = fmaf(x1p[r], cj[u].y, fmaf(x0p[r], cj[u].x, cj[u].z));
                float t0 = max3f(arg[0], arg[1], arg[2]);
                float t1 = max3f(arg[3], arg[4], arg[5]);
                float t2 = max3f(arg[6], arg[7], m[r]);
                float mn = max3f(t0, t1, t2);
                float e0 = exp2_fast(arg[0] - mn) + exp2_fast(arg[1] - mn);
                float e1 = exp2_fast(arg[2] - mn) + exp2_fast(arg[3] - mn);
                float e2 = exp2_fast(arg[4] - mn) + exp2_fast(arg[5] - mn);
                float e3 = exp2_fast(arg[6] - mn) + exp2_fast(arg[7] - mn);
                s[r] = fmaf(s[r], exp2_fast(m[r] - mn), (e0 + e1) + (e2 + e3));
                m[r] = mn;
            }
        }

        // two-phase combine across the 8 j-lanes:
        // max-butterfly -> single rescale -> sum-butterfly (1 exp2 per row)
        float val[2];
        #pragma unroll
        for (int r = 0; r < 2; ++r) {
            float mr = m[r];
            #pragma unroll
            for (int d = 1; d <= 4; d <<= 1) mr = fmaxf(mr, __shfl_xor(mr, d));
            float sr = s[r] * exp2_fast(m[r] - mr);
            #pragma unroll
            for (int d = 1; d <= 4; d <<= 1) sr += __shfl_xor(sr, d);
            val[r] = fmaf(-eps * LN2f, mr + log2_fast(sr), half_n2[r]);
        }

        if (p >= 1 && p <= n_eps) {
            #pragma unroll
            for (int r = 0; r < 2; ++r) val[r] = 0.5f * (pv[r] + val[r]);
        }
        #pragma unroll
        for (int r = 0; r < 2; ++r) pv[r] = val[r];

        if (p == n_pass - 1) break;   // final extrapolation: no write, no barrier

        if (sx == 0) {
            float* dst = (gside ? ((p & 1) ? gB : gA)
                                : ((p & 1) ? fB : fA)) + b * NP + rowbase;
            #pragma unroll
            for (int r = 0; r < 2; ++r)
                __hip_atomic_store(dst + r, val[r], __ATOMIC_RELAXED,
                                   __HIP_MEMORY_SCOPE_AGENT);
        }

        // ---- per-side handshake (wait only on the 8 other-side blocks) ----
        __syncthreads();   // vmcnt(0): our stores visible at the coherence point
        if (tid == 0) {
            __hip_atomic_fetch_add(own_ctr, 1u, __ATOMIC_RELAXED,
                                   __HIP_MEMORY_SCOPE_AGENT);
            const unsigned int target = 8u * (unsigned int)(p + 1);
            unsigned int guard = 0;
            while (__hip_atomic_load(othr_ctr, __ATOMIC_RELAXED,
                                     __HIP_MEMORY_SCOPE_AGENT) < target) {
                __builtin_amdgcn_s_sleep(1);
                if (++guard > (1u << 20)) break;   // valve (never hit when resident)
            }
        }
        __syncthreads();   // others wait for tid0's observation before reading
    }

    // ---- fused weighted dot product of the final extrapolated potentials ----
    float local = 0.0f;
    if (sx == 0) {
        const float2 pr = *(const float2*)(mprob + rowbase);
        local = pr.x * pv[0] + pr.y * pv[1];
    }
    #pragma unroll
    for (int o = 32; o > 0; o >>= 1) local += __shfl_down(local, o);
    if ((tid & 63) == 0) swred[tid >> 6] = local;
    __syncthreads();
    if (tid == 0) part2[bid] = swred[0] + swred[1] + swred[2] + swred[3];
}

// Deterministic final reduction: out = sum_b w[b] * sum_q part2[q*64+b]
__global__ void finred_k(const float* __restrict__ part2,
                         const float* __restrict__ w, float* __restrict__ out) {
    int b = threadIdx.x;   // 64 threads, one wave
    float s = 0.0f;
    #pragma unroll
    for (int u = 0; u < 16; ++u) s += part2[u * 64 + b];
    s *= w[b];
    #pragma unroll
    for (int o = 32; o > 0; o >>= 1) s += __shfl_down(s, o);
    if (b == 0) out[0] = s;
}

extern "C" void kernel_launch(void* const* d_in, const int* in_sizes, int n_in,
                              void* d_out, int out_size, void* d_ws, size_t ws_size,
                              hipStream_t stream) {
    const float* a  = (const float*)d_in[0];  // prob1   [B,N]
    const float* x  = (const float*)d_in[1];  // coord1  [B,N,2]
    const float* bb = (const float*)d_in[2];  // prob2   [B,M]
    const float* y  = (const float*)d_in[3];  // coord2  [B,M,2]
    const float* w  = (const float*)d_in[4];  // weights [B]
    float* out = (float*)d_out;

    // workspace layout
    unsigned char* wsb = (unsigned char*)d_ws;
    unsigned int* bar = (unsigned int*)wsb;              // 64 x 2 counters, 128B apart
    float* part2 = (float*)(wsb + 64 * 64 * 4);          // 1024 floats
    float* fA = (float*)(wsb + 64 * 64 * 4 + 1024 * 4);
    const int NB = B_ * NP;
    float* gA = fA + NB;
    float* fB = gA + NB;
    float* gB = fB + NB;

    // eps schedule (geomloss epsilon_schedule semantics, computed in double)
    EpsList el{};
    int n_eps = 0;
    {
        const double start = 2.0 * std::log(4.0);
        const double stop  = 2.0 * std::log(0.01);
        const double step  = 2.0 * std::log(0.9);
        el.e[n_eps++] = 16.0f;                     // DIAMETER**P
        for (int k = 0;; ++k) {
            double v = start + (double)k * step;
            if (!(v > stop)) break;
            el.e[n_eps++] = (float)std::exp(v);
        }
        el.e[n_eps++] = (float)(0.01 * 0.01);      // BLUR**P
    }

    // counters must restart from 0 on every call (ws poisoned once at start)
    hipMemsetAsync(bar, 0, 64 * 64 * 4, stream);

    sinkhorn_pers<<<dim3(B_ * 16), dim3(256), 0, stream>>>(
        a, x, bb, y, fA, gA, fB, gB, bar, part2, el, n_eps);

    finred_k<<<1, 64, 0, stream>>>(part2, w, out);
}